// Round 12
// baseline (24.069 us; speedup 1.0000x reference)
//
#include <hip/hip_runtime.h>
#include <math.h>

#define EPS_F 1e-8f
#define POISON_U32 0xAAAAAAAAu
#define GRP_SHIFT 5
#define GRP_SIZE  32
#define BLK 1024

__device__ __forceinline__ float rcp_fast(float x) { return __builtin_amdgcn_rcpf(x); }

// ws layout (bytes): gcnt[g] at g*128 (own cachelines); lvl2 at 8192;
// partial[nblocks] at 8448; gpartial[ngroups] after partials.
__launch_bounds__(BLK)
__global__ void iou3d_fused_kernel(const float* __restrict__ g,
                                   const float* __restrict__ q,
                                   float* __restrict__ out,
                                   unsigned char* __restrict__ ws,
                                   int n, int nblocks, float invn) {
    const int tid = threadIdx.x;
    const int grp = blockIdx.x >> GRP_SHIFT;
    unsigned* gcnt = (unsigned*)(ws + (size_t)grp * 128);
    unsigned* lvl2 = (unsigned*)(ws + 8192);
    float* partial = (float*)(ws + 8448);
    float* gpart   = (float*)(ws + 8448 + (size_t)nblocks * 4);

    // Entry de-poison (check-then-CAS), self-cleaning counters -> no-op on clean calls.
    if (tid == 0) {
        unsigned v = __hip_atomic_load(gcnt, __ATOMIC_RELAXED, __HIP_MEMORY_SCOPE_AGENT);
        if (v == POISON_U32) {
            unsigned exp = POISON_U32;
            __hip_atomic_compare_exchange_strong(gcnt, &exp, 0u, __ATOMIC_RELAXED,
                                                 __ATOMIC_RELAXED, __HIP_MEMORY_SCOPE_AGENT);
        }
    }

    // coalesced staging: 1024 boxes x 7 floats per array, loaded as float4
    __shared__ float sgb[BLK * 7];
    __shared__ float sqb[BLK * 7];
    const size_t elemBase = (size_t)blockIdx.x * (BLK * 7);
    const long long availll = (long long)n * 7 - (long long)elemBase;
    const int avail = (availll > BLK * 7) ? BLK * 7 : (int)availll;
    const int avail4 = avail >> 2;
    const float4* g4 = (const float4*)(g + elemBase);
    const float4* q4 = (const float4*)(q + elemBase);
#pragma unroll 2
    for (int i = tid; i < avail4; i += BLK) {
        ((float4*)sgb)[i] = g4[i];
        ((float4*)sqb)[i] = q4[i];
    }
    for (int i = (avail4 << 2) + tid; i < avail; i += BLK) {
        sgb[i] = g[elemBase + i];
        sqb[i] = q[elemBase + i];
    }
    __syncthreads();

    const int gid = blockIdx.x * BLK + tid;
    float loss = 0.0f;
    if (gid < n) {
        const float* gb = sgb + tid * 7;
        const float* qb = sqb + tid * 7;
        const float gx = gb[0], gy = gb[1], gz = gb[2], gh = gb[3], gw = gb[4], gl = gb[5], gr = gb[6];
        const float qx = qb[0], qy = qb[1], qz = qb[2], qh = qb[3], qw = qb[4], ql = qb[5], qr = qb[6];

        float sg, cg, sq_, cq;
        __sincosf(gr, &sg, &cg);
        __sincosf(qr, &sq_, &cq);

        // BEV corners relative to (gx, gz); reference corner order is CW.
        const float LX[4] = {0.5f, 0.5f, -0.5f, -0.5f};
        const float LZ[4] = {0.5f, -0.5f, -0.5f, 0.5f};
        const float dqx = qx - gx, dqz = qz - gz;
        float ax[4], az[4], bx[4], bz[4];
#pragma unroll
        for (int k = 0; k < 4; ++k) {
            const float cxg = LX[k] * gl, czg = LZ[k] * gw;
            ax[k] =  cg * cxg + sg * czg;
            az[k] = -sg * cxg + cg * czg;
            const float cxq = LX[k] * ql, czq = LZ[k] * qw;
            bx[k] =  cq * cxq + sq_ * czq + dqx;
            bz[k] = -sq_ * cxq + cq * czq + dqz;
        }

        float aex[4], aez[4], acc_[4], bex[4], bez[4], bcc[4];
#pragma unroll
        for (int k = 0; k < 4; ++k) {
            aex[k] = ax[(k + 1) & 3] - ax[k];
            aez[k] = az[(k + 1) & 3] - az[k];
            acc_[k] = aex[k] * az[k] - aez[k] * ax[k];
            bex[k] = bx[(k + 1) & 3] - bx[k];
            bez[k] = bz[(k + 1) & 3] - bz[k];
            bcc[k] = bex[k] * bz[k] - bez[k] * bx[k];
        }

        // shared edge-direction crosses + reciprocals (B-loop reuses with sign flips)
        float sm[4][4], rr[4][4];
#pragma unroll
        for (int k = 0; k < 4; ++k)
#pragma unroll
            for (int h = 0; h < 4; ++h) {
                sm[k][h] = bex[h] * aez[k] - bez[h] * aex[k];
                rr[k][h] = rcp_fast(sm[k][h]);
            }

        // Green's theorem: 2*Area = |Σ clipped-segment (t1-t0)*cross(P,d)|
        float total = 0.0f;

        // A edges clipped by B. Parallel-outside (s==+0, f0>0) subsumed by
        // tt = -f0*rcp(+0) = -inf -> t1 = -inf; f0==0 -> NaN ignored by fminf.
#pragma unroll
        for (int k = 0; k < 4; ++k) {
            const float Px = ax[k], Pz = az[k];
            float t0 = 0.0f, t1 = 1.0f;
#pragma unroll
            for (int h = 0; h < 4; ++h) {
                const float s  = sm[k][h];
                const float f0 = bex[h] * Pz - bez[h] * Px - bcc[h];
                const float tt = -f0 * rr[k][h];
                const float c1 = (s >= 0.0f) ? tt : 1e30f;
                const float c0 = (s >= 0.0f) ? -1e30f : tt;
                t1 = fminf(t1, c1);
                t0 = fmaxf(t0, c0);
            }
            total += fmaxf(t1 - t0, 0.0f) * (-acc_[k]);
        }
        // B edges clipped by A (s' = -sm, tt = f0*rr; explicit parallel handling)
#pragma unroll
        for (int h = 0; h < 4; ++h) {
            const float Px = bx[h], Pz = bz[h];
            float t0 = 0.0f, t1 = 1.0f;
#pragma unroll
            for (int k = 0; k < 4; ++k) {
                const float s  = -sm[k][h];
                const float f0 = aex[k] * Pz - aez[k] * Px - acc_[k];
                const float tt = f0 * rr[k][h];
                t1 = (s > 0.0f) ? fminf(t1, tt) : t1;
                t0 = (s < 0.0f) ? fmaxf(t0, tt) : t0;
                t0 = ((s == 0.0f) && (f0 > 0.0f)) ? 1e9f : t0;
            }
            total += fmaxf(t1 - t0, 0.0f) * (-bcc[h]);
        }

        const float area = 0.5f * fabsf(total);

        const float hov = fmaxf(fminf(gy, qy) - fmaxf(gy - gh, qy - qh), 0.0f);
        const float inter = area * hov;
        const float va = gh * gw * gl;
        const float vb = qh * qw * ql;
        float iou = inter / (va + vb - inter + EPS_F);
        iou = fminf(fmaxf(iou, 0.0f), 1.0f);
        loss = 1.0f - iou;
    }

    // deterministic block reduction: wave shfl (width 64) + LDS (16 waves)
#pragma unroll
    for (int off = 32; off > 0; off >>= 1) loss += __shfl_down(loss, off, 64);
    __shared__ float wsum[16];
    __shared__ int roleSh;    // 1 iff this block is its group's last arrival
    __shared__ int finalSh;   // 1 iff this block is the global last
    const int lane = tid & 63;
    const int wid = tid >> 6;
    if (lane == 0) wsum[wid] = loss;
    __syncthreads();

    const int gbase = grp * GRP_SIZE;
    const int gsz = min(GRP_SIZE, nblocks - gbase);
    const int ngroups = (nblocks + GRP_SIZE - 1) >> GRP_SHIFT;

    if (tid == 0) {
        float bs = 0.f;
#pragma unroll
        for (int w = 0; w < 16; ++w) bs += wsum[w];       // fixed order -> deterministic
        // partial ack'd at coherence point before the group ticket increments
        __hip_atomic_store(&partial[blockIdx.x], bs, __ATOMIC_RELAXED, __HIP_MEMORY_SCOPE_AGENT);
        asm volatile("s_waitcnt vmcnt(0)" ::: "memory");
        const unsigned t = __hip_atomic_fetch_add(gcnt, 1u, __ATOMIC_RELAXED, __HIP_MEMORY_SCOPE_AGENT);
        roleSh = (t + 1u == (unsigned)gsz) ? 1 : 0;
        if (roleSh) // all gsz arrivals done -> self-clean for next call
            __hip_atomic_store(gcnt, 0u, __ATOMIC_RELAXED, __HIP_MEMORY_SCOPE_AGENT);
        finalSh = 0;
    }
    __syncthreads();

    if (roleSh) {   // block-uniform branch (shared flag) -> inner syncthreads legal
        // group pre-reduce: fixed lane order -> deterministic
        if (tid < GRP_SIZE) {
            float v = (tid < gsz)
                ? __hip_atomic_load(&partial[gbase + tid], __ATOMIC_RELAXED, __HIP_MEMORY_SCOPE_AGENT)
                : 0.f;
#pragma unroll
            for (int off = 16; off > 0; off >>= 1) v += __shfl_down(v, off, 32);
            if (tid == 0) {
                __hip_atomic_store(&gpart[grp], v, __ATOMIC_RELAXED, __HIP_MEMORY_SCOPE_AGENT);
                asm volatile("s_waitcnt vmcnt(0)" ::: "memory");
                // de-poison level-2 (only group-lasts touch it)
                unsigned w = __hip_atomic_load(lvl2, __ATOMIC_RELAXED, __HIP_MEMORY_SCOPE_AGENT);
                if (w == POISON_U32) {
                    unsigned exp = POISON_U32;
                    __hip_atomic_compare_exchange_strong(lvl2, &exp, 0u, __ATOMIC_RELAXED,
                                                         __ATOMIC_RELAXED, __HIP_MEMORY_SCOPE_AGENT);
                }
                const unsigned u = __hip_atomic_fetch_add(lvl2, 1u, __ATOMIC_RELAXED,
                                                          __HIP_MEMORY_SCOPE_AGENT);
                if (u + 1u == (unsigned)ngroups) {
                    __hip_atomic_store(lvl2, 0u, __ATOMIC_RELAXED, __HIP_MEMORY_SCOPE_AGENT);
                    finalSh = 1;
                }
            }
        }
        __syncthreads();
        if (finalSh && tid == 0) {
            float v = 0.f;
            for (int j = 0; j < ngroups; ++j)             // fixed order -> deterministic
                v += __hip_atomic_load(&gpart[j], __ATOMIC_RELAXED, __HIP_MEMORY_SCOPE_AGENT);
            out[0] = v * invn;
        }
    }
}

extern "C" void kernel_launch(void* const* d_in, const int* in_sizes, int n_in,
                              void* d_out, int out_size, void* d_ws, size_t ws_size,
                              hipStream_t stream) {
    const float* g = (const float*)d_in[0];
    const float* q = (const float*)d_in[1];
    float* out = (float*)d_out;
    const int n = in_sizes[0] / 7;
    const int nblocks = (n + BLK - 1) / BLK;              // 512 for N=524288
    iou3d_fused_kernel<<<nblocks, BLK, 0, stream>>>(g, q, out, (unsigned char*)d_ws,
                                                    n, nblocks, 1.0f / (float)n);
}

// Round 13
// 18.936 us; speedup vs baseline: 1.2711x; 1.2711x over previous
//
#include <hip/hip_runtime.h>
#include <math.h>

#define EPS_F 1e-8f
#define POISON_U32 0xAAAAAAAAu
#define GRP_SHIFT 5
#define GRP_SIZE  32
#define BLK 256
#define BPT 4                      // boxes per thread
#define BOXES (BLK * BPT)          // 1024 boxes per block
#define CHUNK (BOXES * 7)          // 7168 floats per array per block

__device__ __forceinline__ float rcp_fast(float x) { return __builtin_amdgcn_rcpf(x); }

// ws layout (bytes): gcnt[g] at g*128 (own cachelines); lvl2 at 8192;
// partial[nblocks] at 8448; gpartial[ngroups] after partials.
__launch_bounds__(BLK)
__global__ void iou3d_fused_kernel(const float* __restrict__ g,
                                   const float* __restrict__ q,
                                   float* __restrict__ out,
                                   unsigned char* __restrict__ ws,
                                   int n, int nblocks, float invn) {
    const int tid = threadIdx.x;
    const int grp = blockIdx.x >> GRP_SHIFT;
    unsigned* gcnt = (unsigned*)(ws + (size_t)grp * 128);
    unsigned* lvl2 = (unsigned*)(ws + 8192);
    float* partial = (float*)(ws + 8448);
    float* gpart   = (float*)(ws + 8448 + (size_t)nblocks * 4);

    // Entry de-poison (check-then-CAS), self-cleaning counters -> no-op on clean calls.
    if (tid == 0) {
        unsigned v = __hip_atomic_load(gcnt, __ATOMIC_RELAXED, __HIP_MEMORY_SCOPE_AGENT);
        if (v == POISON_U32) {
            unsigned exp = POISON_U32;
            __hip_atomic_compare_exchange_strong(gcnt, &exp, 0u, __ATOMIC_RELAXED,
                                                 __ATOMIC_RELAXED, __HIP_MEMORY_SCOPE_AGENT);
        }
    }

    // coalesced staging: 1024 boxes x 7 floats per array, as float4 (1792 per array)
    __shared__ float sgb[CHUNK];
    __shared__ float sqb[CHUNK];
    const size_t elemBase = (size_t)blockIdx.x * CHUNK;
    const long long availll = (long long)n * 7 - (long long)elemBase;
    if (availll >= CHUNK) {                    // full block (always, for N=524288)
        const float4* g4 = (const float4*)(g + elemBase);
        const float4* q4 = (const float4*)(q + elemBase);
#pragma unroll
        for (int k = 0; k < CHUNK / 4 / BLK; ++k) {
            const int i = tid + k * BLK;
            ((float4*)sgb)[i] = g4[i];
            ((float4*)sqb)[i] = q4[i];
        }
    } else {                                   // generic tail block
        const int avail = (int)availll;
        for (int i = tid; i < avail; i += BLK) {
            sgb[i] = g[elemBase + i];
            sqb[i] = q[elemBase + i];
        }
    }
    __syncthreads();

    float loss = 0.0f;
#pragma unroll
    for (int b = 0; b < BPT; ++b) {
        const int bi = tid + b * BLK;
        const int gid = blockIdx.x * BOXES + bi;
        if (gid >= n) continue;
        // stride-7 LDS reads: 7 coprime 32 -> 2 lanes/bank (free)
        const float* gb = sgb + bi * 7;
        const float* qb = sqb + bi * 7;
        const float gx = gb[0], gy = gb[1], gz = gb[2], gh = gb[3], gw = gb[4], gl = gb[5], gr = gb[6];
        const float qx = qb[0], qy = qb[1], qz = qb[2], qh = qb[3], qw = qb[4], ql = qb[5], qr = qb[6];

        float sg, cg, sq_, cq;
        __sincosf(gr, &sg, &cg);
        __sincosf(qr, &sq_, &cq);

        // BEV corners relative to (gx, gz); reference corner order is CW.
        const float LX[4] = {0.5f, 0.5f, -0.5f, -0.5f};
        const float LZ[4] = {0.5f, -0.5f, -0.5f, 0.5f};
        const float dqx = qx - gx, dqz = qz - gz;
        float ax[4], az[4], bx[4], bz[4];
#pragma unroll
        for (int k = 0; k < 4; ++k) {
            const float cxg = LX[k] * gl, czg = LZ[k] * gw;
            ax[k] =  cg * cxg + sg * czg;
            az[k] = -sg * cxg + cg * czg;
            const float cxq = LX[k] * ql, czq = LZ[k] * qw;
            bx[k] =  cq * cxq + sq_ * czq + dqx;
            bz[k] = -sq_ * cxq + cq * czq + dqz;
        }

        float aex[4], aez[4], acc_[4], bex[4], bez[4], bcc[4];
#pragma unroll
        for (int k = 0; k < 4; ++k) {
            aex[k] = ax[(k + 1) & 3] - ax[k];
            aez[k] = az[(k + 1) & 3] - az[k];
            acc_[k] = aex[k] * az[k] - aez[k] * ax[k];
            bex[k] = bx[(k + 1) & 3] - bx[k];
            bez[k] = bz[(k + 1) & 3] - bz[k];
            bcc[k] = bex[k] * bz[k] - bez[k] * bx[k];
        }

        // shared edge-direction crosses + reciprocals (B-loop reuses with sign flips)
        float sm[4][4], rr[4][4];
#pragma unroll
        for (int k = 0; k < 4; ++k)
#pragma unroll
            for (int h = 0; h < 4; ++h) {
                sm[k][h] = bex[h] * aez[k] - bez[h] * aex[k];
                rr[k][h] = rcp_fast(sm[k][h]);
            }

        // Green's theorem: 2*Area = |Σ clipped-segment (t1-t0)*cross(P,d)|
        // Signed-zero note: x-y in RN never produces -0 for finite x!=y, and
        // fma(a,b,-ab) = +0, so sm==0 is always +0. rcp(+0)=+inf carries the
        // parallel-outside rejection through the select chains below.
        float total = 0.0f;

        // A edges clipped by B: predicate (s >= 0); s==+0 -> c1 = -f0*inf
        // (f0>0 reject, f0<0 pass, f0==0 NaN ignored by fminf).
#pragma unroll
        for (int k = 0; k < 4; ++k) {
            const float Px = ax[k], Pz = az[k];
            float t0 = 0.0f, t1 = 1.0f;
#pragma unroll
            for (int h = 0; h < 4; ++h) {
                const float s  = sm[k][h];
                const float f0 = bex[h] * Pz - bez[h] * Px - bcc[h];
                const float tt = -f0 * rr[k][h];
                t1 = fminf(t1, (s >= 0.0f) ? tt : 1e30f);
                t0 = fmaxf(t0, (s >= 0.0f) ? -1e30f : tt);
            }
            total += fmaxf(t1 - t0, 0.0f) * (-acc_[k]);
        }
        // B edges clipped by A: s' = -sm, tt' = f0*rr; predicate (sm < 0) ⇔ s' > 0.
        // sm==+0 routes to the t0-select: tt' = f0*inf (f0>0 reject, f0<0 pass,
        // f0==0 NaN ignored by fmaxf).
#pragma unroll
        for (int h = 0; h < 4; ++h) {
            const float Px = bx[h], Pz = bz[h];
            float t0 = 0.0f, t1 = 1.0f;
#pragma unroll
            for (int k = 0; k < 4; ++k) {
                const float smv = sm[k][h];
                const float f0 = aex[k] * Pz - aez[k] * Px - acc_[k];
                const float tt = f0 * rr[k][h];
                t1 = fminf(t1, (smv < 0.0f) ? tt : 1e30f);
                t0 = fmaxf(t0, (smv < 0.0f) ? -1e30f : tt);
            }
            total += fmaxf(t1 - t0, 0.0f) * (-bcc[h]);
        }

        const float area = 0.5f * fabsf(total);

        const float hov = fmaxf(fminf(gy, qy) - fmaxf(gy - gh, qy - qh), 0.0f);
        const float inter = area * hov;
        const float va = gh * gw * gl;
        const float vb = qh * qw * ql;
        float iou = inter / (va + vb - inter + EPS_F);
        iou = fminf(fmaxf(iou, 0.0f), 1.0f);
        loss += 1.0f - iou;
    }

    // deterministic block reduction: wave shfl (width 64) + LDS (4 waves)
#pragma unroll
    for (int off = 32; off > 0; off >>= 1) loss += __shfl_down(loss, off, 64);
    __shared__ float wsum[4];
    __shared__ int roleSh;
    __shared__ int finalSh;
    const int lane = tid & 63;
    const int wid = tid >> 6;
    if (lane == 0) wsum[wid] = loss;
    __syncthreads();

    const int gbase = grp * GRP_SIZE;
    const int gsz = min(GRP_SIZE, nblocks - gbase);
    const int ngroups = (nblocks + GRP_SIZE - 1) >> GRP_SHIFT;

    if (tid == 0) {
        const float bs = wsum[0] + wsum[1] + wsum[2] + wsum[3];
        // partial ack'd at coherence point before the group ticket increments
        __hip_atomic_store(&partial[blockIdx.x], bs, __ATOMIC_RELAXED, __HIP_MEMORY_SCOPE_AGENT);
        asm volatile("s_waitcnt vmcnt(0)" ::: "memory");
        const unsigned t = __hip_atomic_fetch_add(gcnt, 1u, __ATOMIC_RELAXED, __HIP_MEMORY_SCOPE_AGENT);
        roleSh = (t + 1u == (unsigned)gsz) ? 1 : 0;
        if (roleSh)   // all arrivals in -> self-clean for next call
            __hip_atomic_store(gcnt, 0u, __ATOMIC_RELAXED, __HIP_MEMORY_SCOPE_AGENT);
        finalSh = 0;
    }
    __syncthreads();

    if (roleSh) {   // block-uniform branch -> inner syncthreads legal
        if (tid < GRP_SIZE) {
            float v = (tid < gsz)
                ? __hip_atomic_load(&partial[gbase + tid], __ATOMIC_RELAXED, __HIP_MEMORY_SCOPE_AGENT)
                : 0.f;
#pragma unroll
            for (int off = 16; off > 0; off >>= 1) v += __shfl_down(v, off, 32);
            if (tid == 0) {
                __hip_atomic_store(&gpart[grp], v, __ATOMIC_RELAXED, __HIP_MEMORY_SCOPE_AGENT);
                asm volatile("s_waitcnt vmcnt(0)" ::: "memory");
                unsigned w = __hip_atomic_load(lvl2, __ATOMIC_RELAXED, __HIP_MEMORY_SCOPE_AGENT);
                if (w == POISON_U32) {
                    unsigned exp = POISON_U32;
                    __hip_atomic_compare_exchange_strong(lvl2, &exp, 0u, __ATOMIC_RELAXED,
                                                         __ATOMIC_RELAXED, __HIP_MEMORY_SCOPE_AGENT);
                }
                const unsigned u = __hip_atomic_fetch_add(lvl2, 1u, __ATOMIC_RELAXED,
                                                          __HIP_MEMORY_SCOPE_AGENT);
                if (u + 1u == (unsigned)ngroups) {
                    __hip_atomic_store(lvl2, 0u, __ATOMIC_RELAXED, __HIP_MEMORY_SCOPE_AGENT);
                    finalSh = 1;
                }
            }
        }
        __syncthreads();
        if (finalSh && tid == 0) {
            float v = 0.f;
            for (int j = 0; j < ngroups; ++j)          // fixed order -> deterministic
                v += __hip_atomic_load(&gpart[j], __ATOMIC_RELAXED, __HIP_MEMORY_SCOPE_AGENT);
            out[0] = v * invn;
        }
    }
}

extern "C" void kernel_launch(void* const* d_in, const int* in_sizes, int n_in,
                              void* d_out, int out_size, void* d_ws, size_t ws_size,
                              hipStream_t stream) {
    const float* g = (const float*)d_in[0];
    const float* q = (const float*)d_in[1];
    float* out = (float*)d_out;
    const int n = in_sizes[0] / 7;
    const int nblocks = (n + BOXES - 1) / BOXES;          // 512 for N=524288
    iou3d_fused_kernel<<<nblocks, BLK, 0, stream>>>(g, q, out, (unsigned char*)d_ws,
                                                    n, nblocks, 1.0f / (float)n);
}

// Round 14
// 15.504 us; speedup vs baseline: 1.5524x; 1.2214x over previous
//
#include <hip/hip_runtime.h>
#include <math.h>

#define EPS_F 1e-8f
#define POISON_U32 0xAAAAAAAAu
#define GRP_SHIFT 5
#define GRP_SIZE  32
#define BLK 256
#define BPT 4                      // boxes per thread
#define BOXES (BLK * BPT)          // 1024 boxes per block
#define CHUNK (BOXES * 7)          // 7168 floats per array per block

__device__ __forceinline__ float rcp_fast(float x) { return __builtin_amdgcn_rcpf(x); }

// slab clip of segment P + t*d, t in [0,1], against |x|<=hx, |z|<=hz, given rd = 1/d.
// Parallel-outside -> +/-inf pair -> len 0; parallel-inside -> -inf/+inf -> no constraint;
// exactly-on-boundary-parallel -> NaN -> dropped by minNum/maxNum (measure-zero).
__device__ __forceinline__ float clip_len(float Px, float Pz, float rdx, float rdz,
                                          float hx, float hz) {
    const float tx0 = (-hx - Px) * rdx;
    const float tx1 = ( hx - Px) * rdx;
    const float tz0 = (-hz - Pz) * rdz;
    const float tz1 = ( hz - Pz) * rdz;
    const float t0 = fmaxf(fmaxf(fminf(tx0, tx1), fminf(tz0, tz1)), 0.0f);  // v_max3
    const float t1 = fminf(fminf(fmaxf(tx0, tx1), fmaxf(tz0, tz1)), 1.0f);  // v_min3
    return fmaxf(t1 - t0, 0.0f);
}

// ws layout (bytes): gcnt[g] at g*128 (own cachelines); lvl2 at 8192;
// partial[nblocks] at 8448; gpartial[ngroups] after partials.
__launch_bounds__(BLK)
__global__ void iou3d_fused_kernel(const float* __restrict__ g,
                                   const float* __restrict__ q,
                                   float* __restrict__ out,
                                   unsigned char* __restrict__ ws,
                                   int n, int nblocks, float invn) {
    const int tid = threadIdx.x;
    const int grp = blockIdx.x >> GRP_SHIFT;
    unsigned* gcnt = (unsigned*)(ws + (size_t)grp * 128);
    unsigned* lvl2 = (unsigned*)(ws + 8192);
    float* partial = (float*)(ws + 8448);
    float* gpart   = (float*)(ws + 8448 + (size_t)nblocks * 4);

    // Entry de-poison (check-then-CAS), self-cleaning counters -> no-op on clean calls.
    if (tid == 0) {
        unsigned v = __hip_atomic_load(gcnt, __ATOMIC_RELAXED, __HIP_MEMORY_SCOPE_AGENT);
        if (v == POISON_U32) {
            unsigned exp = POISON_U32;
            __hip_atomic_compare_exchange_strong(gcnt, &exp, 0u, __ATOMIC_RELAXED,
                                                 __ATOMIC_RELAXED, __HIP_MEMORY_SCOPE_AGENT);
        }
    }

    // coalesced staging: 1024 boxes x 7 floats per array, as float4
    __shared__ float sgb[CHUNK];
    __shared__ float sqb[CHUNK];
    const size_t elemBase = (size_t)blockIdx.x * CHUNK;
    const long long availll = (long long)n * 7 - (long long)elemBase;
    if (availll >= CHUNK) {
        const float4* g4 = (const float4*)(g + elemBase);
        const float4* q4 = (const float4*)(q + elemBase);
#pragma unroll
        for (int k = 0; k < CHUNK / 4 / BLK; ++k) {
            const int i = tid + k * BLK;
            ((float4*)sgb)[i] = g4[i];
            ((float4*)sqb)[i] = q4[i];
        }
    } else {
        const int avail = (int)availll;
        for (int i = tid; i < avail; i += BLK) {
            sgb[i] = g[elemBase + i];
            sqb[i] = q[elemBase + i];
        }
    }
    __syncthreads();

    float loss = 0.0f;
#pragma unroll
    for (int b = 0; b < BPT; ++b) {
        const int bi = tid + b * BLK;
        const int gid = blockIdx.x * BOXES + bi;
        if (gid >= n) continue;
        const float* gb = sgb + bi * 7;
        const float* qb = sqb + bi * 7;
        const float gx = gb[0], gy = gb[1], gz = gb[2], gh = gb[3], gw = gb[4], gl = gb[5], gr = gb[6];
        const float qx = qb[0], qy = qb[1], qz = qb[2], qh = qb[3], qw = qb[4], ql = qb[5], qr = qb[6];

        float sg, cg, sq_, cq;
        __sincosf(gr, &sg, &cg);
        __sincosf(qr, &sq_, &cq);

        const float hla = 0.5f * gl, hwa = 0.5f * gw;
        const float hlq = 0.5f * ql, hwq = 0.5f * qw;

        // relative rotation phi = (qr - gr): M = [[cr,-sr],[sr,cr]] maps B-local -> A-local
        const float cr = cg * cq + sg * sq_;
        const float sr = sg * cq - cg * sq_;
        const float dqx = qx - gx, dqz = qz - gz;

        // ---- B's corners/edges in A's local frame (A's rect is axis-aligned there) ----
        const float Tx = cg * dqx - sg * dqz;          // R_A^T * dq
        const float Tz = sg * dqx + cg * dqz;
        const float E1x = cr * hlq,  E1z = sr * hlq;   // M*(hlq,0)
        const float E2x = -sr * hwq, E2z = cr * hwq;   // M*(0,hwq)
        const float q0x = Tx + E1x + E2x, q0z = Tz + E1z + E2z;
        const float q1x = Tx + E1x - E2x, q1z = Tz + E1z - E2z;
        const float q2x = Tx - E1x - E2x, q2z = Tz - E1z - E2z;
        const float q3x = Tx - E1x + E2x, q3z = Tz - E1z + E2z;
        // edge dirs: d0=-2E2, d1=-2E1, d2=+2E2, d3=+2E1 (opposite edges antiparallel)
        const float F1x = E1x + E1x, F1z = E1z + E1z;
        const float F2x = E2x + E2x, F2z = E2z + E2z;
        const float rF1x = rcp_fast(F1x), rF1z = rcp_fast(F1z);
        const float rF2x = rcp_fast(F2x), rF2z = rcp_fast(F2z);

        // Green's theorem: 2*Area(A∩B) = |sum over clipped boundary of cross(P,d)*(t1-t0)|
        // (t-interval is frame-invariant; contributions all evaluated in A's frame)
        float total = 0.0f;
        {
            const float l0 = clip_len(q0x, q0z, -rF2x, -rF2z, hla, hwa);
            const float c0 = q0x * F2z - q0z * F2x;          // cross(q0, F2); d0 = -F2
            total = fmaf(l0, -c0, total);
            const float l1 = clip_len(q1x, q1z, -rF1x, -rF1z, hla, hwa);
            const float c1 = q1x * F1z - q1z * F1x;
            total = fmaf(l1, -c1, total);
            const float l2 = clip_len(q2x, q2z,  rF2x,  rF2z, hla, hwa);
            const float c2 = q2x * F2z - q2z * F2x;
            total = fmaf(l2, c2, total);
            const float l3 = clip_len(q3x, q3z,  rF1x,  rF1z, hla, hwa);
            const float c3 = q3x * F1z - q3z * F1x;
            total = fmaf(l3, c3, total);
        }

        // ---- A's corners/edges in B's local frame (clip target axis-aligned) ----
        // A-edge contribution in A's own frame: cross(P,d) = -(gl*gw)/2, SAME for all
        // 4 edges -> only the total clipped length is needed.
        const float Ux = -(cq * dqx - sq_ * dqz);      // R_B^T * (-dq)
        const float Uz = -(sq_ * dqx + cq * dqz);
        const float G1x = cr * hla,  G1z = -sr * hla;  // M^T*(hla,0)
        const float G2x = sr * hwa,  G2z = cr * hwa;   // M^T*(0,hwa)
        const float p0x = Ux + G1x + G2x, p0z = Uz + G1z + G2z;
        const float p1x = Ux + G1x - G2x, p1z = Uz + G1z - G2z;
        const float p2x = Ux - G1x - G2x, p2z = Uz - G1z - G2z;
        const float p3x = Ux - G1x + G2x, p3z = Uz - G1z + G2z;
        const float H1x = G1x + G1x, H1z = G1z + G1z;
        const float H2x = G2x + G2x, H2z = G2z + G2z;
        const float rH1x = rcp_fast(H1x), rH1z = rcp_fast(H1z);
        const float rH2x = rcp_fast(H2x), rH2z = rcp_fast(H2z);

        const float m0 = clip_len(p0x, p0z, -rH2x, -rH2z, hlq, hwq);
        const float m1 = clip_len(p1x, p1z, -rH1x, -rH1z, hlq, hwq);
        const float m2 = clip_len(p2x, p2z,  rH2x,  rH2z, hlq, hwq);
        const float m3 = clip_len(p3x, p3z,  rH1x,  rH1z, hlq, hwq);
        const float glw = gl * gw;
        total = fmaf((m0 + m1) + (m2 + m3), -0.5f * glw, total);

        const float area2 = fabsf(total);              // = 2*Area

        const float hov = fmaxf(fminf(gy, qy) - fmaxf(gy - gh, qy - qh), 0.0f);
        const float inter = 0.5f * area2 * hov;
        const float va = gh * glw;
        const float vb = qh * qw * ql;
        float iou = inter / (va + vb - inter + EPS_F);
        iou = fminf(fmaxf(iou, 0.0f), 1.0f);
        loss += 1.0f - iou;
    }

    // deterministic block reduction: wave shfl (width 64) + LDS (4 waves)
#pragma unroll
    for (int off = 32; off > 0; off >>= 1) loss += __shfl_down(loss, off, 64);
    __shared__ float wsum[4];
    __shared__ int roleSh;
    __shared__ int finalSh;
    const int lane = tid & 63;
    const int wid = tid >> 6;
    if (lane == 0) wsum[wid] = loss;
    __syncthreads();

    const int gbase = grp * GRP_SIZE;
    const int gsz = min(GRP_SIZE, nblocks - gbase);
    const int ngroups = (nblocks + GRP_SIZE - 1) >> GRP_SHIFT;

    if (tid == 0) {
        const float bs = wsum[0] + wsum[1] + wsum[2] + wsum[3];
        __hip_atomic_store(&partial[blockIdx.x], bs, __ATOMIC_RELAXED, __HIP_MEMORY_SCOPE_AGENT);
        asm volatile("s_waitcnt vmcnt(0)" ::: "memory");
        const unsigned t = __hip_atomic_fetch_add(gcnt, 1u, __ATOMIC_RELAXED, __HIP_MEMORY_SCOPE_AGENT);
        roleSh = (t + 1u == (unsigned)gsz) ? 1 : 0;
        if (roleSh)
            __hip_atomic_store(gcnt, 0u, __ATOMIC_RELAXED, __HIP_MEMORY_SCOPE_AGENT);
        finalSh = 0;
    }
    __syncthreads();

    if (roleSh) {   // block-uniform branch -> inner syncthreads legal
        if (tid < GRP_SIZE) {
            float v = (tid < gsz)
                ? __hip_atomic_load(&partial[gbase + tid], __ATOMIC_RELAXED, __HIP_MEMORY_SCOPE_AGENT)
                : 0.f;
#pragma unroll
            for (int off = 16; off > 0; off >>= 1) v += __shfl_down(v, off, 32);
            if (tid == 0) {
                __hip_atomic_store(&gpart[grp], v, __ATOMIC_RELAXED, __HIP_MEMORY_SCOPE_AGENT);
                asm volatile("s_waitcnt vmcnt(0)" ::: "memory");
                unsigned w = __hip_atomic_load(lvl2, __ATOMIC_RELAXED, __HIP_MEMORY_SCOPE_AGENT);
                if (w == POISON_U32) {
                    unsigned exp = POISON_U32;
                    __hip_atomic_compare_exchange_strong(lvl2, &exp, 0u, __ATOMIC_RELAXED,
                                                         __ATOMIC_RELAXED, __HIP_MEMORY_SCOPE_AGENT);
                }
                const unsigned u = __hip_atomic_fetch_add(lvl2, 1u, __ATOMIC_RELAXED,
                                                          __HIP_MEMORY_SCOPE_AGENT);
                if (u + 1u == (unsigned)ngroups) {
                    __hip_atomic_store(lvl2, 0u, __ATOMIC_RELAXED, __HIP_MEMORY_SCOPE_AGENT);
                    finalSh = 1;
                }
            }
        }
        __syncthreads();
        if (finalSh && tid == 0) {
            float v = 0.f;
            for (int j = 0; j < ngroups; ++j)
                v += __hip_atomic_load(&gpart[j], __ATOMIC_RELAXED, __HIP_MEMORY_SCOPE_AGENT);
            out[0] = v * invn;
        }
    }
}

extern "C" void kernel_launch(void* const* d_in, const int* in_sizes, int n_in,
                              void* d_out, int out_size, void* d_ws, size_t ws_size,
                              hipStream_t stream) {
    const float* g = (const float*)d_in[0];
    const float* q = (const float*)d_in[1];
    float* out = (float*)d_out;
    const int n = in_sizes[0] / 7;
    const int nblocks = (n + BOXES - 1) / BOXES;          // 512 for N=524288
    iou3d_fused_kernel<<<nblocks, BLK, 0, stream>>>(g, q, out, (unsigned char*)d_ws,
                                                    n, nblocks, 1.0f / (float)n);
}